// Round 1
// baseline (2664.726 us; speedup 1.0000x reference)
//
#include <hip/hip_runtime.h>
#include <math.h>

#define Bx   8
#define Nx   5000
#define Kx   16
#define DINx 128
#define Hx   128
#define G4x  512
#define Mx   40000

__device__ __forceinline__ float sigf(float v) {
    return __fdividef(1.0f, 1.0f + __expf(-v));
}
// tanh via exp, saturates cleanly to +-1 without NaN at large |v|
__device__ __forceinline__ float tanf_(float v) {
    return 1.0f - __fdividef(2.0f, __expf(2.0f * v) + 1.0f);
}

#define FMA4(P, A, Q)                                        \
    P = fmaf((A).x, (Q).x, P); P = fmaf((A).y, (Q).y, P);    \
    P = fmaf((A).z, (Q).z, P); P = fmaf((A).w, (Q).w, P);

// ---------------------------------------------------------------------------
// Kernel A: G[m][0:512] = W_ih @ x[m]   (no bias; bias folded into kb)
//           S[m][0:128] = W_self @ x[m] + b_self
// block = 128 threads, 8 nodes/block, 5 output cols/thread (640 = 128*5)
// ---------------------------------------------------------------------------
__global__ __launch_bounds__(128) void ka(const float* __restrict__ x,
        const float* __restrict__ W_ih, const float* __restrict__ W_self,
        const float* __restrict__ b_self, float* __restrict__ G,
        float* __restrict__ S)
{
    __shared__ float xs[8 * DINx];
    const int m0 = blockIdx.x * 8;
    {
        const float4* src = (const float4*)(x + (size_t)m0 * DINx);
        float4* dst = (float4*)xs;
        #pragma unroll
        for (int i = 0; i < 2; ++i)
            dst[threadIdx.x + 128 * i] = src[threadIdx.x + 128 * i];
    }
    __syncthreads();

    const int t = threadIdx.x;
    const float4* wp[5];
    #pragma unroll
    for (int c = 0; c < 5; ++c) {
        const int o = t + 128 * c;
        wp[c] = (const float4*)((o < G4x) ? (W_ih + (size_t)o * DINx)
                                          : (W_self + (size_t)(o - G4x) * DINx));
    }
    float acc[8][5];
    #pragma unroll
    for (int n = 0; n < 8; ++n)
        #pragma unroll
        for (int c = 0; c < 5; ++c) acc[n][c] = 0.f;

    #pragma unroll 4
    for (int k4 = 0; k4 < 32; ++k4) {
        float4 wv[5];
        #pragma unroll
        for (int c = 0; c < 5; ++c) wv[c] = wp[c][k4];
        #pragma unroll
        for (int n = 0; n < 8; ++n) {
            const float4 xv = ((const float4*)(xs + n * DINx))[k4];
            #pragma unroll
            for (int c = 0; c < 5; ++c) { FMA4(acc[n][c], xv, wv[c]); }
        }
    }
    const float bs = b_self[t];
    #pragma unroll
    for (int n = 0; n < 8; ++n) {
        const size_t m = (size_t)(m0 + n);
        #pragma unroll
        for (int c = 0; c < 4; ++c)
            G[m * G4x + t + 128 * c] = acc[n][c];
        S[m * Hx + t] = acc[n][4] + bs;
    }
}

// ---------------------------------------------------------------------------
// Kernel B: fused LSTM recurrence over 16 neighbor steps + output head.
// 512 threads, 64 sequences/block. Thread (sg,dg) owns seqs sg*4+i (i<4),
// dims dg*4+j (j<4). W_hh staged per 128-gate chunk into LDS with a
// float4-column XOR swizzle (c ^ ((r>>2)&31)) to break stride-128 conflicts.
// ---------------------------------------------------------------------------
__global__ __launch_bounds__(512, 2) void kb(const float* __restrict__ G,
        const float* __restrict__ S, const int* __restrict__ nidx,
        const float* __restrict__ nw, const float* __restrict__ W_hh,
        const float* __restrict__ b_ih, const float* __restrict__ b_hh,
        const float* __restrict__ W_comb, const float* __restrict__ b_comb,
        float* __restrict__ out)
{
    __shared__ float hs[64 * Hx];     // 32 KB  current hidden state
    __shared__ float Wc[128 * 128];   // 64 KB  W_hh chunk (swizzled)
    __shared__ int   gofs[64 * Kx];   // 4 KB   gathered G row offsets
    __shared__ float wts[64 * Kx];    // 4 KB   neighbor weights

    const int tid = threadIdx.x;
    const int dg = tid & 31;
    const int sg = tid >> 5;
    const int m0 = blockIdx.x * 64;

    for (int i = tid; i < 64 * Kx; i += 512) {
        const int s = i >> 4, k = i & 15;
        const int m = m0 + s;
        const int b = m / Nx;
        const int n = m - b * Nx;
        gofs[i] = (b * Nx + nidx[n * Kx + k]) * G4x;
        wts[i]  = nw[n * Kx + k];
    }
    {
        const float4 z = make_float4(0.f, 0.f, 0.f, 0.f);
        float4* h4 = (float4*)hs;
        #pragma unroll
        for (int i = 0; i < 4; ++i) h4[tid + 512 * i] = z;  // 2048 float4s
    }
    float bias[4][4];
    #pragma unroll
    for (int q = 0; q < 4; ++q) {
        const float4 bi = ((const float4*)b_ih)[q * 32 + dg];
        const float4 bh = ((const float4*)b_hh)[q * 32 + dg];
        bias[q][0] = bi.x + bh.x; bias[q][1] = bi.y + bh.y;
        bias[q][2] = bi.z + bh.z; bias[q][3] = bi.w + bh.w;
    }
    float cst[4][4];
    #pragma unroll
    for (int i = 0; i < 4; ++i)
        #pragma unroll
        for (int j = 0; j < 4; ++j) cst[i][j] = 0.f;

    __syncthreads();

    float p[4][4][4];  // gate pre-activations: [gate-type][seq][dim]

    #pragma unroll 1
    for (int k = 0; k < Kx; ++k) {
        float wk[4]; int gr[4];
        #pragma unroll
        for (int i = 0; i < 4; ++i) {
            const int s = sg * 4 + i;
            wk[i] = wts[s * Kx + k];
            gr[i] = gofs[s * Kx + k];
        }
        #pragma unroll
        for (int q = 0; q < 4; ++q) {
            float4 xg[4];  // gathered input-gate contributions (issued early)
            #pragma unroll
            for (int i = 0; i < 4; ++i)
                xg[i] = *(const float4*)(G + (size_t)gr[i] + q * Hx + dg * 4);
            #pragma unroll
            for (int i = 0; i < 4; ++i)
                #pragma unroll
                for (int j = 0; j < 4; ++j) p[q][i][j] = 0.f;

            if (k > 0) {
                // stage W_hh rows [q*128, q*128+128) into Wc, f4-col swizzled
                #pragma unroll
                for (int r8 = 0; r8 < 8; ++r8) {
                    const int L = r8 * 512 + tid;       // f4 linear idx
                    const int r = L >> 5, cs = L & 31;
                    const float4 v =
                        ((const float4*)W_hh)[(size_t)(q * 128 + r) * 32 + cs];
                    ((float4*)Wc)[r * 32 + (cs ^ ((r >> 2) & 31))] = v;
                }
                __syncthreads();
                #pragma unroll 8
                for (int k4 = 0; k4 < 32; ++k4) {
                    float4 hv[4], wv[4];
                    #pragma unroll
                    for (int i = 0; i < 4; ++i)
                        hv[i] = ((const float4*)(hs + (sg * 4 + i) * Hx))[k4];
                    #pragma unroll
                    for (int j = 0; j < 4; ++j)   // row=dg*4+j → swz col = k4^dg
                        wv[j] = ((const float4*)Wc)[(dg * 4 + j) * 32 + (k4 ^ dg)];
                    #pragma unroll
                    for (int i = 0; i < 4; ++i) {
                        #pragma unroll
                        for (int j = 0; j < 4; ++j) { FMA4(p[q][i][j], hv[i], wv[j]); }
                    }
                }
            }
            // gates += w * gathered_G + (b_ih + b_hh)
            #pragma unroll
            for (int i = 0; i < 4; ++i) {
                p[q][i][0] += wk[i] * xg[i].x + bias[q][0];
                p[q][i][1] += wk[i] * xg[i].y + bias[q][1];
                p[q][i][2] += wk[i] * xg[i].z + bias[q][2];
                p[q][i][3] += wk[i] * xg[i].w + bias[q][3];
            }
            if (k > 0) __syncthreads();  // before next chunk overwrites Wc
        }
        // activations (PyTorch gate order i,f,g,o) + c/h update
        #pragma unroll
        for (int i = 0; i < 4; ++i) {
            float hn[4];
            #pragma unroll
            for (int j = 0; j < 4; ++j) {
                const float ig = sigf(p[0][i][j]);
                const float fg = sigf(p[1][i][j]);
                const float gg = tanf_(p[2][i][j]);
                const float og = sigf(p[3][i][j]);
                const float cc = fg * cst[i][j] + ig * gg;
                cst[i][j] = cc;
                hn[j] = og * tanf_(cc);
            }
            *(float4*)(hs + (sg * 4 + i) * Hx + dg * 4) =
                make_float4(hn[0], hn[1], hn[2], hn[3]);
        }
    }
    __syncthreads();

    // epilogue: out = relu([S, h] @ W_comb^T + b_comb)
    float acc[4][4];
    #pragma unroll
    for (int i = 0; i < 4; ++i)
        #pragma unroll
        for (int j = 0; j < 4; ++j) acc[i][j] = 0.f;

    const float4* S4 = (const float4*)S;
    const float4* W4 = (const float4*)W_comb;  // 64 f4 per output row
    #pragma unroll 4
    for (int d4 = 0; d4 < 32; ++d4) {
        float4 sv[4], wv[4];
        #pragma unroll
        for (int i = 0; i < 4; ++i)
            sv[i] = S4[(size_t)(m0 + sg * 4 + i) * 32 + d4];
        #pragma unroll
        for (int j = 0; j < 4; ++j) wv[j] = W4[(dg * 4 + j) * 64 + d4];
        #pragma unroll
        for (int i = 0; i < 4; ++i) {
            #pragma unroll
            for (int j = 0; j < 4; ++j) { FMA4(acc[i][j], sv[i], wv[j]); }
        }
    }
    #pragma unroll 4
    for (int d4 = 0; d4 < 32; ++d4) {
        float4 hv[4], wv[4];
        #pragma unroll
        for (int i = 0; i < 4; ++i)
            hv[i] = ((const float4*)(hs + (sg * 4 + i) * Hx))[d4];
        #pragma unroll
        for (int j = 0; j < 4; ++j) wv[j] = W4[(dg * 4 + j) * 64 + 32 + d4];
        #pragma unroll
        for (int i = 0; i < 4; ++i) {
            #pragma unroll
            for (int j = 0; j < 4; ++j) { FMA4(acc[i][j], hv[i], wv[j]); }
        }
    }
    const float4 bc = ((const float4*)b_comb)[dg];
    #pragma unroll
    for (int i = 0; i < 4; ++i) {
        float4 o4;
        o4.x = fmaxf(acc[i][0] + bc.x, 0.f);
        o4.y = fmaxf(acc[i][1] + bc.y, 0.f);
        o4.z = fmaxf(acc[i][2] + bc.z, 0.f);
        o4.w = fmaxf(acc[i][3] + bc.w, 0.f);
        *(float4*)(out + (size_t)(m0 + sg * 4 + i) * Hx + dg * 4) = o4;
    }
}

extern "C" void kernel_launch(void* const* d_in, const int* in_sizes, int n_in,
                              void* d_out, int out_size, void* d_ws, size_t ws_size,
                              hipStream_t stream)
{
    const float* x      = (const float*)d_in[0];
    const int*   nidx   = (const int*)  d_in[1];
    const float* nw     = (const float*)d_in[2];
    const float* W_ih   = (const float*)d_in[3];
    const float* W_hh   = (const float*)d_in[4];
    const float* b_ih   = (const float*)d_in[5];
    const float* b_hh   = (const float*)d_in[6];
    const float* W_self = (const float*)d_in[7];
    const float* b_self = (const float*)d_in[8];
    const float* W_comb = (const float*)d_in[9];
    const float* b_comb = (const float*)d_in[10];
    float* out = (float*)d_out;

    float* G = (float*)d_ws;                   // 40000*512 floats = 81.92 MB
    float* S = G + (size_t)Mx * G4x;           // 40000*128 floats = 20.48 MB

    ka<<<Mx / 8, 128, 0, stream>>>(x, W_ih, W_self, b_self, G, S);
    kb<<<Mx / 64, 512, 0, stream>>>(G, S, nidx, nw, W_hh, b_ih, b_hh,
                                    W_comb, b_comb, out);
}

// Round 4
// 1423.452 us; speedup vs baseline: 1.8720x; 1.8720x over previous
//
#include <hip/hip_runtime.h>
#include <math.h>

#define Bx   8
#define Nx   5000
#define Kx   16
#define DINx 128
#define Hx   128
#define G4x  512
#define Mx   40000

typedef __attribute__((ext_vector_type(8))) short sh8;   // 8 bf16 (4 VGPR)
typedef __attribute__((ext_vector_type(4))) float f32x4; // MFMA acc

__device__ __forceinline__ float sigf(float v) {
    return __fdividef(1.0f, 1.0f + __expf(-v));
}
__device__ __forceinline__ float tanf_(float v) {
    return 1.0f - __fdividef(2.0f, __expf(2.0f * v) + 1.0f);
}
__device__ __forceinline__ unsigned short rne16(float f) {
    unsigned int u = __float_as_uint(f);
    return (unsigned short)((u + 0x7fffu + ((u >> 16) & 1u)) >> 16);
}
__device__ __forceinline__ float b2f(unsigned short s) {
    return __uint_as_float(((unsigned int)s) << 16);
}

#define FMA4(P, A, Q)                                        \
    P = fmaf((A).x, (Q).x, P); P = fmaf((A).y, (Q).y, P);    \
    P = fmaf((A).z, (Q).z, P); P = fmaf((A).w, (Q).w, P);

// ---------------------------------------------------------------------------
// Kernel A: G[m][0:512] = W_ih @ x[m];  S[m] = W_self@x[m]+b_self
// ---------------------------------------------------------------------------
__global__ __launch_bounds__(128) void ka(const float* __restrict__ x,
        const float* __restrict__ W_ih, const float* __restrict__ W_self,
        const float* __restrict__ b_self, float* __restrict__ G,
        float* __restrict__ S)
{
    __shared__ float xs[8 * DINx];
    const int m0 = blockIdx.x * 8;
    {
        const float4* src = (const float4*)(x + (size_t)m0 * DINx);
        float4* dst = (float4*)xs;
        #pragma unroll
        for (int i = 0; i < 2; ++i)
            dst[threadIdx.x + 128 * i] = src[threadIdx.x + 128 * i];
    }
    __syncthreads();

    const int t = threadIdx.x;
    const float4* wp[5];
    #pragma unroll
    for (int c = 0; c < 5; ++c) {
        const int o = t + 128 * c;
        wp[c] = (const float4*)((o < G4x) ? (W_ih + (size_t)o * DINx)
                                          : (W_self + (size_t)(o - G4x) * DINx));
    }
    float acc[8][5];
    #pragma unroll
    for (int n = 0; n < 8; ++n)
        #pragma unroll
        for (int c = 0; c < 5; ++c) acc[n][c] = 0.f;

    #pragma unroll 4
    for (int k4 = 0; k4 < 32; ++k4) {
        float4 wv[5];
        #pragma unroll
        for (int c = 0; c < 5; ++c) wv[c] = wp[c][k4];
        #pragma unroll
        for (int n = 0; n < 8; ++n) {
            const float4 xv = ((const float4*)(xs + n * DINx))[k4];
            #pragma unroll
            for (int c = 0; c < 5; ++c) { FMA4(acc[n][c], xv, wv[c]); }
        }
    }
    const float bs = b_self[t];
    #pragma unroll
    for (int n = 0; n < 8; ++n) {
        const size_t m = (size_t)(m0 + n);
        #pragma unroll
        for (int c = 0; c < 4; ++c)
            G[m * G4x + t + 128 * c] = acc[n][c];
        S[m * Hx + t] = acc[n][4] + bs;
    }
}

// ---------------------------------------------------------------------------
// Kernel W: split W_hh into bf16 hi + bf16 residual lo; bsum = b_ih + b_hh
// ---------------------------------------------------------------------------
__global__ __launch_bounds__(256) void kw(const float* __restrict__ W_hh,
        const float* __restrict__ b_ih, const float* __restrict__ b_hh,
        unsigned short* __restrict__ WH, unsigned short* __restrict__ WL,
        float* __restrict__ bsum)
{
    const int i = blockIdx.x * 256 + threadIdx.x;
    if (i < G4x * Hx) {
        const float w = W_hh[i];
        const unsigned short hi = rne16(w);
        WH[i] = hi;
        WL[i] = rne16(w - b2f(hi));
    }
    if (i < G4x) bsum[i] = b_ih[i] + b_hh[i];
}

// ---------------------------------------------------------------------------
// Kernel B: LSTM recurrence via split-bf16 MFMA. 256 thr (4 waves), 32 seqs.
// Wave v owns dims 32v..32v+32 of ALL 4 gates; both 16-seq M-tiles.
// h in LDS as bf16 hi/lo, XOR-granule swizzled. W streamed from L2.
// 2 barriers/step. Fused [S,h]@W_comb^T epilogue.
// ---------------------------------------------------------------------------
__global__ __launch_bounds__(256) void kb(const float* __restrict__ G,
        const float* __restrict__ S, const unsigned short* __restrict__ WH,
        const unsigned short* __restrict__ WL, const float* __restrict__ bsum,
        const int* __restrict__ nidx, const float* __restrict__ nw,
        const float* __restrict__ W_comb, const float* __restrict__ b_comb,
        float* __restrict__ out)
{
    __shared__ unsigned short hsHI[32 * 128];  // 8 KB
    __shared__ unsigned short hsLO[32 * 128];  // 8 KB
    __shared__ float hsF[32 * 136];            // 17.4 KB (final h, f32, padded)
    __shared__ int   gofs[16 * 32];            // [k][seq]
    __shared__ float wts [16 * 32];

    const int tid    = threadIdx.x;
    const int lane   = tid & 63;
    const int v      = tid >> 6;        // wave 0..3
    const int row16  = lane & 15;
    const int quad   = lane >> 4;       // 0..3
    const int swzkey = row16 & 7;
    const int dimb   = v * 32;
    const int m0     = blockIdx.x * 32;

    for (int i = tid; i < 512; i += 256) {
        const int s = i & 31, kk = i >> 5;
        const int m = m0 + s;
        const int bb = m / Nx;
        const int nn = m - bb * Nx;
        gofs[kk * 32 + s] = (bb * Nx + nidx[nn * Kx + kk]) * G4x;
        wts [kk * 32 + s] = nw[nn * Kx + kk];
    }
    float bsv[4][2];
    #pragma unroll
    for (int g = 0; g < 4; ++g)
        #pragma unroll
        for (int b2 = 0; b2 < 2; ++b2)
            bsv[g][b2] = bsum[g * 128 + dimb + 16 * b2 + row16];

    float cst[2][2][4];
    #pragma unroll
    for (int mt = 0; mt < 2; ++mt)
        #pragma unroll
        for (int b2 = 0; b2 < 2; ++b2)
            #pragma unroll
            for (int j = 0; j < 4; ++j) cst[mt][b2][j] = 0.f;

    __syncthreads();

    #pragma unroll 1
    for (int k = 0; k < Kx; ++k) {
        // ---- gather G rows (issued early; lands during MFMA phase) ----
        float wkv[2][4];
        const float* gp[2][4];
        #pragma unroll
        for (int mt = 0; mt < 2; ++mt)
            #pragma unroll
            for (int j = 0; j < 4; ++j) {
                const int seq = mt * 16 + quad * 4 + j;
                wkv[mt][j] = wts[k * 32 + seq];
                gp[mt][j]  = G + gofs[k * 32 + seq] + dimb + row16;
            }
        float gld[2][4][4][2];
        #pragma unroll
        for (int mt = 0; mt < 2; ++mt)
            #pragma unroll
            for (int j = 0; j < 4; ++j)
                #pragma unroll
                for (int g = 0; g < 4; ++g)
                    #pragma unroll
                    for (int b2 = 0; b2 < 2; ++b2)
                        gld[mt][j][g][b2] = gp[mt][j][(g << 7) + (b2 << 4)];

        f32x4 acc[2][4][2];
        #pragma unroll
        for (int mt = 0; mt < 2; ++mt)
            #pragma unroll
            for (int g = 0; g < 4; ++g)
                #pragma unroll
                for (int b2 = 0; b2 < 2; ++b2)
                    acc[mt][g][b2] = (f32x4)0.f;

        if (k) {  // h == 0 at k == 0
            #pragma unroll
            for (int kt = 0; kt < 4; ++kt) {
                sh8 ahi[2], alo[2];
                #pragma unroll
                for (int mt = 0; mt < 2; ++mt) {
                    const int ro = ((mt * 16 + row16) << 7) +
                                   ((((kt << 2) + quad) ^ swzkey) << 3);
                    ahi[mt] = *(const sh8*)(hsHI + ro);
                    alo[mt] = *(const sh8*)(hsLO + ro);
                }
                #pragma unroll
                for (int b2 = 0; b2 < 2; ++b2) {
                    #pragma unroll
                    for (int g = 0; g < 4; ++g) {
                        const int nro = ((g << 7) + dimb + (b2 << 4) + row16) * 128
                                        + (kt << 5) + (quad << 3);
                        const sh8 wh = *(const sh8*)(WH + nro);
                        const sh8 wl = *(const sh8*)(WL + nro);
                        #pragma unroll
                        for (int mt = 0; mt < 2; ++mt) {
                            acc[mt][g][b2] = __builtin_amdgcn_mfma_f32_16x16x32_bf16(
                                ahi[mt], wh, acc[mt][g][b2], 0, 0, 0);
                            acc[mt][g][b2] = __builtin_amdgcn_mfma_f32_16x16x32_bf16(
                                alo[mt], wh, acc[mt][g][b2], 0, 0, 0);
                            acc[mt][g][b2] = __builtin_amdgcn_mfma_f32_16x16x32_bf16(
                                ahi[mt], wl, acc[mt][g][b2], 0, 0, 0);
                        }
                    }
                }
            }
        }

        // ---- activations (registers only) ----
        float hval[2][2][4];
        #pragma unroll
        for (int mt = 0; mt < 2; ++mt)
            #pragma unroll
            for (int b2 = 0; b2 < 2; ++b2)
                #pragma unroll
                for (int j = 0; j < 4; ++j) {
                    const float pi = acc[mt][0][b2][j] + wkv[mt][j] * gld[mt][j][0][b2] + bsv[0][b2];
                    const float pf = acc[mt][1][b2][j] + wkv[mt][j] * gld[mt][j][1][b2] + bsv[1][b2];
                    const float pg = acc[mt][2][b2][j] + wkv[mt][j] * gld[mt][j][2][b2] + bsv[2][b2];
                    const float po = acc[mt][3][b2][j] + wkv[mt][j] * gld[mt][j][3][b2] + bsv[3][b2];
                    const float ig = sigf(pi), fg = sigf(pf);
                    const float gg = tanf_(pg), og = sigf(po);
                    const float cc = fg * cst[mt][b2][j] + ig * gg;
                    cst[mt][b2][j] = cc;
                    hval[mt][b2][j] = og * tanf_(cc);
                }

        __syncthreads();  // all hs reads of this step done before overwrite

        if (k < Kx - 1) {
            #pragma unroll
            for (int mt = 0; mt < 2; ++mt)
                #pragma unroll
                for (int b2 = 0; b2 < 2; ++b2)
                    #pragma unroll
                    for (int j = 0; j < 4; ++j) {
                        const int seq = mt * 16 + quad * 4 + j;
                        const int dim = dimb + (b2 << 4) + row16;
                        const int idx = (seq << 7) +
                                        ((((dim >> 3) ^ (seq & 7))) << 3) + (dim & 7);
                        const float f = hval[mt][b2][j];
                        const unsigned short hi = rne16(f);
                        hsHI[idx] = hi;
                        hsLO[idx] = rne16(f - b2f(hi));
                    }
        } else {  // final step: park h as f32 for the epilogue
            #pragma unroll
            for (int mt = 0; mt < 2; ++mt)
                #pragma unroll
                for (int b2 = 0; b2 < 2; ++b2)
                    #pragma unroll
                    for (int j = 0; j < 4; ++j) {
                        const int seq = mt * 16 + quad * 4 + j;
                        const int dim = dimb + (b2 << 4) + row16;
                        hsF[seq * 136 + dim] = hval[mt][b2][j];
                    }
        }
        __syncthreads();  // writes visible before next step's reads
    }

    // ---- epilogue: out = relu([S, h] @ W_comb^T + b_comb) ----
    const int dg = tid & 31;
    const int sg = tid >> 5;  // 0..7 -> seqs sg*4..+4
    float ac[4][4];
    #pragma unroll
    for (int i = 0; i < 4; ++i)
        #pragma unroll
        for (int j = 0; j < 4; ++j) ac[i][j] = 0.f;

    const float4* S4 = (const float4*)S;
    const float4* W4 = (const float4*)W_comb;
    #pragma unroll 4
    for (int d4 = 0; d4 < 32; ++d4) {
        float4 sv[4], wv[4];
        #pragma unroll
        for (int i = 0; i < 4; ++i)
            sv[i] = S4[(size_t)(m0 + sg * 4 + i) * 32 + d4];
        #pragma unroll
        for (int j = 0; j < 4; ++j) wv[j] = W4[(dg * 4 + j) * 64 + d4];
        #pragma unroll
        for (int i = 0; i < 4; ++i) {
            #pragma unroll
            for (int j = 0; j < 4; ++j) { FMA4(ac[i][j], sv[i], wv[j]); }
        }
    }
    #pragma unroll 4
    for (int d4 = 0; d4 < 32; ++d4) {
        float4 hv[4], wv[4];
        #pragma unroll
        for (int i = 0; i < 4; ++i)
            hv[i] = *(const float4*)(hsF + (sg * 4 + i) * 136 + d4 * 4);
        #pragma unroll
        for (int j = 0; j < 4; ++j) wv[j] = W4[(dg * 4 + j) * 64 + 32 + d4];
        #pragma unroll
        for (int i = 0; i < 4; ++i) {
            #pragma unroll
            for (int j = 0; j < 4; ++j) { FMA4(ac[i][j], hv[i], wv[j]); }
        }
    }
    const float4 bc = ((const float4*)b_comb)[dg];
    #pragma unroll
    for (int i = 0; i < 4; ++i) {
        float4 o4;
        o4.x = fmaxf(ac[i][0] + bc.x, 0.f);
        o4.y = fmaxf(ac[i][1] + bc.y, 0.f);
        o4.z = fmaxf(ac[i][2] + bc.z, 0.f);
        o4.w = fmaxf(ac[i][3] + bc.w, 0.f);
        *(float4*)(out + (size_t)(m0 + sg * 4 + i) * 128 + dg * 4) = o4;
    }
}

extern "C" void kernel_launch(void* const* d_in, const int* in_sizes, int n_in,
                              void* d_out, int out_size, void* d_ws, size_t ws_size,
                              hipStream_t stream)
{
    const float* x      = (const float*)d_in[0];
    const int*   nidx   = (const int*)  d_in[1];
    const float* nw     = (const float*)d_in[2];
    const float* W_ih   = (const float*)d_in[3];
    const float* W_hh   = (const float*)d_in[4];
    const float* b_ih   = (const float*)d_in[5];
    const float* b_hh   = (const float*)d_in[6];
    const float* W_self = (const float*)d_in[7];
    const float* b_self = (const float*)d_in[8];
    const float* W_comb = (const float*)d_in[9];
    const float* b_comb = (const float*)d_in[10];
    float* out = (float*)d_out;

    float* G = (float*)d_ws;                         // 40000*512 f32 = 81.92 MB
    float* S = G + (size_t)Mx * G4x;                 // 40000*128 f32 = 20.48 MB
    unsigned short* WH = (unsigned short*)(S + (size_t)Mx * Hx);  // 128 KB
    unsigned short* WL = WH + (size_t)G4x * Hx;                   // 128 KB
    float* bsum = (float*)(WL + (size_t)G4x * Hx);                // 2 KB

    kw<<<(G4x * Hx + 255) / 256, 256, 0, stream>>>(W_hh, b_ih, b_hh, WH, WL, bsum);
    ka<<<Mx / 8, 128, 0, stream>>>(x, W_ih, W_self, b_self, G, S);
    kb<<<Mx / 32, 256, 0, stream>>>(G, S, WH, WL, bsum, nidx, nw,
                                    W_comb, b_comb, out);
}